// Round 1
// 247.418 us; speedup vs baseline: 1.0165x; 1.0165x over previous
//
#include <hip/hip_runtime.h>

#define MAXLEN 100
#define HDIM 64
#define CH 4                       // x-staging chunk length (steps)
#define NSEG 12                    // segments per block (12 real rows of 16)
#define SROW 72                    // ushorts per bf16 x step-row (144 B)
#define SPLANE (CH * SROW + 8)     // 296 ushorts per segment plane
#define HSTR 72                    // ushorts per h row (144 B)
#define L2E 1.44269504f

typedef __attribute__((ext_vector_type(8))) short bf16x8;
typedef __attribute__((ext_vector_type(4))) float f32x4;

// Step barrier: LDS-only consistency (no implicit vmcnt(0) drain), so the
// chunk-ahead x prefetch stays in flight across all step barriers.
#define LGKM_BARRIER() asm volatile("s_waitcnt lgkmcnt(0)\n\ts_barrier" ::: "memory")

__device__ __forceinline__ unsigned short f2bf_u(float f) {   // RNE f32->bf16
    unsigned u = __float_as_uint(f);
    u += 0x7fffu + ((u >> 16) & 1u);
    return (unsigned short)(u >> 16);
}
__device__ __forceinline__ unsigned pk2(float a, float b) {
    return (unsigned)f2bf_u(a) | ((unsigned)f2bf_u(b) << 16);
}
__device__ __forceinline__ bf16x8 pack8(f32x4 a, f32x4 b) {
    union { unsigned u[4]; bf16x8 v; } c;
    c.u[0] = pk2(a[0], a[1]); c.u[1] = pk2(a[2], a[3]);
    c.u[2] = pk2(b[0], b[1]); c.u[3] = pk2(b[2], b[3]);
    return c.v;
}
// sigmoid(v + b) with bs = -L2E*b folded into the exp2 argument.
__device__ __forceinline__ float sig_b(float v, float bs) {
    return __builtin_amdgcn_rcpf(1.0f + __builtin_amdgcn_exp2f(fmaf(v, -L2E, bs)));
}
__device__ __forceinline__ float tanh_b(float v, float bs2) {
    return fmaf(2.0f, __builtin_amdgcn_rcpf(1.0f + __builtin_amdgcn_exp2f(fmaf(v, -2.0f * L2E, bs2))), -1.0f);
}
__device__ __forceinline__ float tanh_p(float v) {
    return fmaf(2.0f, __builtin_amdgcn_rcpf(1.0f + __builtin_amdgcn_exp2f(v * (-2.0f * L2E))), -1.0f);
}

// ---------------------------------------------------------------------------
// Pre-pass A: segment boundaries from the sorted index array.
// segStart[s] = first row i with index[i] >= s, for s in [0, B]; segStart[B]=N.
// ---------------------------------------------------------------------------
__global__ void seg_bounds_kernel(const int* __restrict__ index,
                                  int* __restrict__ segStart, int N, int B) {
    const int i = blockIdx.x * blockDim.x + threadIdx.x;
    if (i >= N) return;
    const int a = index[i];
    const int prev = (i == 0) ? -1 : index[i - 1];
    for (int s = prev + 1; s <= a; ++s) segStart[s] = i;
    if (i == N - 1) {
        for (int s = a + 1; s <= B; ++s) segStart[s] = N;
    }
}

// ---------------------------------------------------------------------------
// Pre-pass B: counting sort of segments by length (descending), 101 buckets.
// slotSeg/slotStart/slotLen[slot] describe the segment assigned to that slot;
// block b of the main kernel takes slots [b*NSEG, b*NSEG+NSEG) -> all its
// segments have (nearly) equal length, so lmax ~= mean instead of max-of-12.
// Tail slots (>= B) get seg=-1, len=0.
// ---------------------------------------------------------------------------
__global__ void seg_sort_kernel(const int* __restrict__ segStart,
                                int* __restrict__ slotSeg,
                                int* __restrict__ slotStart,
                                int* __restrict__ slotLen, int B, int nslots) {
    __shared__ int hist[MAXLEN + 1];
    __shared__ int base[MAXLEN + 1];
    __shared__ int cnt[MAXLEN + 1];
    const int tid = threadIdx.x;   // 1024 threads
    if (tid <= MAXLEN) { hist[tid] = 0; cnt[tid] = 0; }
    __syncthreads();
    for (int b = tid; b < B; b += 1024) {
        int len = segStart[b + 1] - segStart[b];
        len = len < MAXLEN ? len : MAXLEN;
        atomicAdd(&hist[len], 1);
    }
    __syncthreads();
    if (tid == 0) {
        int acc = 0;
        for (int l = MAXLEN; l >= 0; --l) { base[l] = acc; acc += hist[l]; }
    }
    __syncthreads();
    for (int b = tid; b < B; b += 1024) {
        const int s0 = segStart[b];
        int len = segStart[b + 1] - s0;
        len = len < MAXLEN ? len : MAXLEN;
        const int slot = base[len] + atomicAdd(&cnt[len], 1);
        slotSeg[slot] = b; slotStart[slot] = s0; slotLen[slot] = len;
    }
    for (int s = B + tid; s < nslots; s += 1024) {
        slotSeg[s] = -1; slotStart[s] = 0; slotLen[s] = 0;
    }
}

// 683 blocks x 256 threads; 12 segments/block; 4 waves, wave w owns hidden
// cols [16w,16w+16) for all 4 gates. Segment s -> MFMA A/C row (s/3)*4+(s%3);
// each lane's C regs 0..2 are its 3 real (seg,hid) bundles; garbage A rows
// need no zeroing (C-row independence).
// The per-step MFMA chain is split: accx[g] = x_t @ Wih (2-deep,
// h-independent) is computed in the PREVIOUS step's trans shadow; the serial
// step seeds the h-chain with it: acc = mfma(ha1,wh1, mfma(ha0,wh0,accx)).
// NEW vs R0: segments arrive length-sorted through slot arrays (counting-sort
// pre-pass), so a block's 12 segments have ~equal length -> lmax ~= mean(len)
// (was max-of-12), removing ~18% frozen-step work and staggering block
// finishes (tail blocks run on a draining, low-contention machine).
__global__ __launch_bounds__(256, 3)
void lstm12_kernel(const float* __restrict__ x,
                   const float* __restrict__ Wih,
                   const float* __restrict__ Whh,
                   const float* __restrict__ bih,
                   const float* __restrict__ bhh,
                   const int* __restrict__ index,
                   const int* __restrict__ slotSeg,
                   const int* __restrict__ slotStart,
                   const int* __restrict__ slotLen,
                   float* __restrict__ out, int N, int B) {
    const int tid  = threadIdx.x;
    const int w    = tid >> 6;
    const int lane = tid & 63;
    const int l15  = lane & 15;
    const int quad = lane >> 4;
    const int segbase = blockIdx.x * NSEG;
    const int ncol = w * 16 + l15;

    __shared__ __align__(16) unsigned short xst[NSEG * SPLANE];  // 7.1 KB
    __shared__ __align__(16) unsigned short hst[2][16][HSTR];    // 4.6 KB
    __shared__ int sstart[NSEG], slen[NSEG], sseg[NSEG];

    // --- per-block segment bounds: sorted slots if available, else search ---
    if (tid < NSEG) {
        const int slot = segbase + tid;
        int sg = -1, s = 0, len = 0;
        if (slotSeg != nullptr) {
            sg  = slotSeg[slot];
            s   = slotStart[slot];
            len = slotLen[slot];
        } else {
            const int b = slot;
            if (b < B) {
                sg = b;
                int lo = 0, hi = N;
                while (lo < hi) { int m = (lo + hi) >> 1; if (index[m] < b) lo = m + 1; else hi = m; }
                s = lo;
                hi = N;
                while (lo < hi) { int m = (lo + hi) >> 1; if (index[m] < b + 1) lo = m + 1; else hi = m; }
                len = lo - s;
                len = len < MAXLEN ? len : MAXLEN;
            }
        }
        sstart[tid] = s;
        slen[tid] = len;
        sseg[tid] = sg;
    }
    for (int i = tid; i < 2 * 16 * HSTR / 2; i += 256) ((int*)hst)[i] = 0;
    __syncthreads();

    // --- weight B-fragments (register-resident) + exp-folded biases ---
    bf16x8 wi[4][2], wh[4][2];
    float bs[4];
#pragma unroll
    for (int g = 0; g < 4; ++g) {
        const int row = g * HDIM + ncol;
        const float bb = bih[row] + bhh[row];
        bs[g] = (g == 2) ? (-2.0f * L2E) * bb : (-L2E) * bb;
#pragma unroll
        for (int kt = 0; kt < 2; ++kt) {
            const f32x4* pi = (const f32x4*)(Wih + (size_t)row * HDIM + kt * 32 + quad * 8);
            const f32x4* ph = (const f32x4*)(Whh + (size_t)row * HDIM + kt * 32 + quad * 8);
            wi[g][kt] = pack8(pi[0], pi[1]);
            wh[g][kt] = pack8(ph[0], ph[1]);
        }
    }

    // Per-lane gate-math metadata: segs quad*3 + r, r in 0..2.
    int len3[3];
#pragma unroll
    for (int r = 0; r < 3; ++r) len3[r] = slen[quad * 3 + r];
    int lmax = 0;
#pragma unroll
    for (int i = 0; i < NSEG; ++i) { int v = slen[i]; lmax = v > lmax ? v : lmax; }
    lmax = __builtin_amdgcn_readfirstlane(lmax);

    // Staging roles: 12 segs x 4 steps x 4 col-groups(16 floats) = 192 units;
    // waves 0..2 stage (tid < 192), wave 3 idle in staging. pre = 16 VGPRs.
    const int sS = tid >> 4, sT = (tid >> 2) & 3, sC = tid & 3;   // valid for tid<192
    const int sst = (tid < 192) ? sstart[sS] : 0;
    const int sln = (tid < 192) ? slen[sS] : 0;

    f32x4 pre[4];

#define ISSUE(t0_)                                                              \
    if (w < 3) {                                                                \
        int ct = (t0_) + sT;                                                    \
        ct = (sln > 0) ? (ct < sln ? ct : sln - 1) : 0;                         \
        int row = sst + ct;                                                     \
        row = row < N - 1 ? row : N - 1;                                        \
        const f32x4* p_ = (const f32x4*)(x + (size_t)row * HDIM + sC * 16);     \
        pre[0] = p_[0]; pre[1] = p_[1]; pre[2] = p_[2]; pre[3] = p_[3];         \
    }
#define COMMIT()                                                                \
    if (w < 3) {                                                                \
        uint4 o1, o2;                                                           \
        o1.x = pk2(pre[0][0], pre[0][1]); o1.y = pk2(pre[0][2], pre[0][3]);     \
        o1.z = pk2(pre[1][0], pre[1][1]); o1.w = pk2(pre[1][2], pre[1][3]);     \
        o2.x = pk2(pre[2][0], pre[2][1]); o2.y = pk2(pre[2][2], pre[2][3]);     \
        o2.z = pk2(pre[3][0], pre[3][1]); o2.w = pk2(pre[3][2], pre[3][3]);     \
        unsigned short* d_ = &xst[sS * SPLANE + sT * SROW + sC * 16];           \
        *(uint4*)d_ = o1; *(uint4*)(d_ + 8) = o2;                               \
    }

    // x A-frag source plane for this lane's A-row m=l15: real seg
    // (m>>2)*3 + min(m&3,2); garbage rows alias a real plane (broadcast, free).
    const int m3 = l15 & 3;
    const int xp = (l15 >> 2) * 3 + (m3 < 2 ? m3 : 2);
    const unsigned short* xb = &xst[xp * SPLANE + quad * 8];

    // accx[g] = x_t @ Wih for the upcoming step (h-independent 2-deep chain).
    f32x4 accx[4];
#define ACCX(tt_)                                                               \
    {                                                                           \
        const unsigned short* xr_ = xb + (tt_) * SROW;                          \
        bf16x8 xa0_ = *(const bf16x8*)(xr_);                                    \
        bf16x8 xa1_ = *(const bf16x8*)(xr_ + 32);                               \
        _Pragma("unroll")                                                       \
        for (int g_ = 0; g_ < 4; ++g_) {                                        \
            f32x4 a_ = __builtin_amdgcn_mfma_f32_16x16x32_bf16(xa0_, wi[g_][0], cz, 0, 0, 0); \
            accx[g_] = __builtin_amdgcn_mfma_f32_16x16x32_bf16(xa1_, wi[g_][1], a_, 0, 0, 0); \
        }                                                                       \
    }

    float c3[3] = {0, 0, 0}, h3[3] = {0, 0, 0};
    const f32x4 cz = {0.0f, 0.0f, 0.0f, 0.0f};
    const int nch = (lmax + CH - 1) / CH;

    if (nch > 0) {
        ISSUE(0);
        COMMIT();                      // compiler auto-waits vmcnt for pre use
        LGKM_BARRIER();
        ACCX(0);                       // x-part of step 0
        if (nch > 1) ISSUE(CH);        // chunk 1 in flight across chunk 0's steps

        for (int ch = 0; ch < nch; ++ch) {
            const int t0 = ch * CH;
#pragma unroll
            for (int tt = 0; tt < CH; ++tt) {
                const int t = t0 + tt;          // parity(t) == parity(tt), CH even
                const int pb = tt & 1, nb = pb ^ 1;

                // h-dependent half: 2-deep chain seeded by accx.
                const unsigned short* hr = &hst[pb][l15][quad * 8];
                bf16x8 ha0 = *(const bf16x8*)(hr);
                bf16x8 ha1 = *(const bf16x8*)(hr + 32);

                f32x4 acc[4];
#pragma unroll
                for (int g = 0; g < 4; ++g) {
                    f32x4 a = __builtin_amdgcn_mfma_f32_16x16x32_bf16(ha0, wh[g][0], accx[g], 0, 0, 0);
                    acc[g] = __builtin_amdgcn_mfma_f32_16x16x32_bf16(ha1, wh[g][1], a, 0, 0, 0);
                }

                // x-part of the NEXT step (independent of h): fills the
                // MFMA pipe while this step's gate trans runs.
                if (tt + 1 < CH) ACCX(tt + 1);

                // Gate math: 3 real bundles/lane (C regs 0..2 = segs 3q..3q+2).
#pragma unroll
                for (int r = 0; r < 3; ++r) {
                    float gi = sig_b (acc[0][r], bs[0]);
                    float gf = sig_b (acc[1][r], bs[1]);
                    float gg = tanh_b(acc[2][r], bs[2]);
                    float go = sig_b (acc[3][r], bs[3]);
                    float cn = fmaf(gf, c3[r], gi * gg);
                    float hn = go * tanh_p(cn);
                    const bool up = t < len3[r];
                    c3[r] = up ? cn : c3[r];
                    h3[r] = up ? hn : h3[r];
                    hst[nb][quad * 4 + r][ncol] = f2bf_u(h3[r]);
                }
                LGKM_BARRIER();
            }
            if (ch + 1 < nch) {
                COMMIT();                          // chunk ch+1 (vmcnt auto-waited)
                LGKM_BARRIER();
                ACCX(0);                           // x-part of next chunk's step 0
                if (ch + 2 < nch) ISSUE((ch + 2) * CH);
            }
        }
    }

#pragma unroll
    for (int r = 0; r < 3; ++r) {
        const int sg = sseg[quad * 3 + r];
        if (sg >= 0) out[(size_t)sg * HDIM + ncol] = h3[r];
    }
#undef ISSUE
#undef COMMIT
#undef ACCX
}

extern "C" void kernel_launch(void* const* d_in, const int* in_sizes, int n_in,
                              void* d_out, int out_size, void* d_ws, size_t ws_size,
                              hipStream_t stream) {
    const float* x     = (const float*)d_in[0];
    const float* Wih   = (const float*)d_in[1];
    const float* Whh   = (const float*)d_in[2];
    const float* bih   = (const float*)d_in[3];
    const float* bhh   = (const float*)d_in[4];
    const int*   index = (const int*)d_in[5];

    const int N = in_sizes[5];
    const int B = out_size / HDIM;   // 8192

    const int nblocks = (B + NSEG - 1) / NSEG;   // 683
    const int nslots  = nblocks * NSEG;

    // Workspace layout: segStart[B+1] | slotSeg[nslots] | slotStart[nslots] | slotLen[nslots]
    const int segStartInts = (B + 1 + 3) & ~3;   // 16B-aligned region
    const size_t need = ((size_t)segStartInts + 3 * (size_t)nslots) * sizeof(int);
    const bool sortOK = (d_ws != nullptr) && (ws_size >= need) && (B <= 16384);

    if (sortOK) {
        int* segStart  = (int*)d_ws;
        int* slotSeg   = segStart + segStartInts;
        int* slotStart = slotSeg + nslots;
        int* slotLen   = slotStart + nslots;
        const int ablocks = (N + 255) / 256;
        seg_bounds_kernel<<<ablocks, 256, 0, stream>>>(index, segStart, N, B);
        seg_sort_kernel<<<1, 1024, 0, stream>>>(segStart, slotSeg, slotStart, slotLen, B, nslots);
        lstm12_kernel<<<nblocks, 256, 0, stream>>>(x, Wih, Whh, bih, bhh, index,
                                                   slotSeg, slotStart, slotLen,
                                                   (float*)d_out, N, B);
    } else {
        lstm12_kernel<<<nblocks, 256, 0, stream>>>(x, Wih, Whh, bih, bhh, index,
                                                   nullptr, nullptr, nullptr,
                                                   (float*)d_out, N, B);
    }
}